// Round 1
// baseline (35173.615 us; speedup 1.0000x reference)
//
#include <hip/hip_runtime.h>
#include <cstdint>
#include <cstddef>

#define NWG   256
#define NTH   512
#define LSTEP 1024
#define NB    64     // batch
#define KD    512    // MEM
#define ID    128    // IN

// ws layout:
// [0, 8192)              barrier counters (1025 used)
// [8192, 8192+131072)    hfA  (transposed [512][64] fp32)
// [8192+131072, +131072) hfB

__device__ __forceinline__ void gbar(unsigned* cnt, int id) {
  __syncthreads();
  if (threadIdx.x == 0) {
    __threadfence();  // agent-scope release of our global writes
    __hip_atomic_fetch_add(&cnt[id], 1u, __ATOMIC_RELEASE, __HIP_MEMORY_SCOPE_AGENT);
    while (__hip_atomic_load(&cnt[id], __ATOMIC_ACQUIRE, __HIP_MEMORY_SCOPE_AGENT) < (unsigned)NWG) {
      __builtin_amdgcn_s_sleep(2);
    }
    __threadfence();  // acquire: invalidate stale L1/L2 before reading others' hf
  }
  __syncthreads();
}

__global__ void __launch_bounds__(NTH)
fused_scan(const float* __restrict__ u, const float* __restrict__ h0,
           const float* __restrict__ Wi, const float* __restrict__ bi,
           const float* __restrict__ Wm, const float* __restrict__ bm,
           float* __restrict__ out, float* __restrict__ hfA,
           float* __restrict__ hfB, unsigned* __restrict__ cnt)
{
  // LDS: 24576 + 8192 + 20480 + 2560 + 512 + 512 + 64 + 64 = 56960 B
  __shared__ float wm_s[KD * 12];   // me-cols c=0..9 at slot (c/5)*6 + c%5 (pitch 12)
  __shared__ float wi_s[ID * 16];   // ie-cols c=0..11 at slot (c/3)*4 + c%3 (pitch 16)
  __shared__ float part[5120];      // me: [kc8][r64][c10]; ie (reused): [kc4][r64][c12]
  __shared__ float me_s[640];       // reduced me [r64][c10]
  __shared__ float hf_own[128];     // [r64][jj2]
  __shared__ float hs_own[128];
  __shared__ float bm_s[16];
  __shared__ float bi_s[16];

  const int wg   = blockIdx.x;   // 0..255
  const int j0   = wg * 2;       // this WG owns hf columns j0, j0+1
  const int tid  = threadIdx.x;
  const int w    = tid >> 6;     // wave 0..7
  const int lane = tid & 63;

  // ---- one-time: load Wm slice (512 k-rows x 10 cols), each thread one k-row
  {
    const int k = tid;
    const float* wrow = Wm + (size_t)k * 2560 + j0;
    #pragma unroll
    for (int c = 0; c < 10; ++c) {
      wm_s[k * 12 + (c / 5) * 6 + (c % 5)] = wrow[(c >> 1) * 512 + (c & 1)];
    }
  }
  // ---- one-time: load Wi slice (128 k-rows x 12 cols)
  if (tid < ID) {
    const int k = tid;
    const float* wrow = Wi + (size_t)k * 3072 + j0;
    #pragma unroll
    for (int c = 0; c < 12; ++c) {
      wi_s[k * 16 + (c / 3) * 4 + (c % 3)] = wrow[(c >> 1) * 512 + (c & 1)];
    }
  }
  if (tid < 10) bm_s[tid] = bm[(tid >> 1) * 512 + j0 + (tid & 1)];
  if (tid >= 32 && tid < 44) {
    const int c = tid - 32;
    bi_s[c] = bi[(c >> 1) * 512 + j0 + (c & 1)];
  }
  // ---- init own hf/hs from h0, publish hf slice to hfA (transposed [j][b])
  if (tid < 128) {
    const int r = tid >> 1, jj = tid & 1;
    const float f = h0[(size_t)r * 512 + j0 + jj];
    const float s = h0[(size_t)32768 + r * 512 + j0 + jj];
    hf_own[tid] = f;
    hs_own[tid] = s;
    hfA[(j0 + jj) * 64 + r] = f;
  }
  gbar(cnt, 0);

  for (int st = 0; st < LSTEP; ++st) {
    const float* __restrict__ hfc = (st & 1) ? hfB : hfA;
    float* __restrict__ hfw       = (st & 1) ? hfA : hfB;

    // ======== phase 1: me partials. wave w handles k in [w*64, w*64+64) ========
    {
      const int rg    = lane >> 1;   // 0..31 -> rows rr, rr+1
      const int cg    = lane & 1;    // 0..1  -> me-cols cg*5 .. cg*5+4
      const int cslot = cg * 6;
      const int kb    = w * 64;
      const float2* __restrict__ hp = (const float2*)hfc;  // [k][32] float2
      float acc00 = 0, acc01 = 0, acc02 = 0, acc03 = 0, acc04 = 0;
      float acc10 = 0, acc11 = 0, acc12 = 0, acc13 = 0, acc14 = 0;
      float2 pf0 = hp[(kb + 0) * 32 + rg];
      float2 pf1 = hp[(kb + 1) * 32 + rg];
      float2 pf2 = hp[(kb + 2) * 32 + rg];
      float2 pf3 = hp[(kb + 3) * 32 + rg];

#define ME_ITER(KI, PFV)                                                   \
      {                                                                    \
        const int k_ = kb + (KI);                                          \
        const float2 cur = PFV;                                            \
        PFV = hp[(kb + (((KI) + 4) & 63)) * 32 + rg];                      \
        const float2* wp = (const float2*)&wm_s[k_ * 12 + cslot];          \
        const float2 wab = wp[0];                                          \
        const float2 wcd = wp[1];                                          \
        const float  we  = wm_s[k_ * 12 + cslot + 4];                      \
        acc00 += cur.x * wab.x; acc01 += cur.x * wab.y;                    \
        acc02 += cur.x * wcd.x; acc03 += cur.x * wcd.y;                    \
        acc04 += cur.x * we;                                               \
        acc10 += cur.y * wab.x; acc11 += cur.y * wab.y;                    \
        acc12 += cur.y * wcd.x; acc13 += cur.y * wcd.y;                    \
        acc14 += cur.y * we;                                               \
      }

      for (int ki4 = 0; ki4 < 64; ki4 += 4) {
        ME_ITER(ki4 + 0, pf0)
        ME_ITER(ki4 + 1, pf1)
        ME_ITER(ki4 + 2, pf2)
        ME_ITER(ki4 + 3, pf3)
      }
#undef ME_ITER

      const int rr = rg * 2;
      float* pp = &part[w * 640 + rr * 10 + cg * 5];
      pp[0]  = acc00; pp[1]  = acc01; pp[2]  = acc02; pp[3]  = acc03; pp[4]  = acc04;
      pp[10] = acc10; pp[11] = acc11; pp[12] = acc12; pp[13] = acc13; pp[14] = acc14;
    }
    __syncthreads();

    // ======== phase 2: reduce me partials (+bm) into me_s ========
    {
      float v = bm_s[tid % 10];
      #pragma unroll
      for (int kc = 0; kc < 8; ++kc) v += part[kc * 640 + tid];
      me_s[tid] = v;
      if (tid < 128) {
        const int o = tid + 512;
        float v2 = bm_s[o % 10];
        #pragma unroll
        for (int kc = 0; kc < 8; ++kc) v2 += part[kc * 640 + o];
        me_s[o] = v2;
      }
    }
    __syncthreads();

    // ======== phase 3: ie partials (u[:,st,:] @ Wi slice), reuse part ========
    {
      const int kc   = w >> 1;                 // 0..3, k in [kc*32, kc*32+32)
      const int tile = ((w & 1) << 6) + lane;  // 0..127
      const int rg   = tile >> 2;              // 0..31
      const int cg   = tile & 3;               // 0..3 -> ie-cols cg*3..cg*3+2
      const int rr   = rg * 2;
      const int cb   = cg * 4;
      const int kb   = kc * 32;
      const float* __restrict__ u0 = u + (size_t)rr * 131072 + (size_t)st * 128 + kb;
      const float* __restrict__ u1 = u0 + 131072;
      float a00 = 0, a01 = 0, a02 = 0, a10 = 0, a11 = 0, a12 = 0;
      #pragma unroll 4
      for (int ki = 0; ki < 32; ++ki) {
        const int k_ = kb + ki;
        const float x0 = u0[ki];
        const float x1 = u1[ki];
        const float2* wp = (const float2*)&wi_s[k_ * 16 + cb];
        const float2 wab = wp[0];
        const float  wc  = wi_s[k_ * 16 + cb + 2];
        a00 += x0 * wab.x; a01 += x0 * wab.y; a02 += x0 * wc;
        a10 += x1 * wab.x; a11 += x1 * wab.y; a12 += x1 * wc;
      }
      float* pp = &part[kc * 768 + rr * 12 + cg * 3];
      pp[0]  = a00; pp[1]  = a01; pp[2]  = a02;
      pp[12] = a10; pp[13] = a11; pp[14] = a12;
    }
    __syncthreads();

    // ======== phase 4: elementwise gate update for own (r, jj) ========
    if (tid < 128) {
      const int r = tid >> 1, jj = tid & 1;
      const float m0 = me_s[r * 10 + 0 + jj];
      const float m1 = me_s[r * 10 + 2 + jj];
      const float m2 = me_s[r * 10 + 4 + jj];
      const float m3 = me_s[r * 10 + 6 + jj];
      const float m4 = me_s[r * 10 + 8 + jj];
      float i0 = bi_s[0 + jj], i1 = bi_s[2 + jj], i2 = bi_s[4 + jj];
      float i3 = bi_s[6 + jj], i4 = bi_s[8 + jj], i5 = bi_s[10 + jj];
      #pragma unroll
      for (int kc = 0; kc < 4; ++kc) {
        const float* pp = &part[kc * 768 + r * 12];
        i0 += pp[0 + jj]; i1 += pp[2 + jj]; i2 += pp[4 + jj];
        i3 += pp[6 + jj]; i4 += pp[8 + jj]; i5 += pp[10 + jj];
      }
      const float hf = hf_own[tid];
      const float hs = hs_own[tid];
      const float ta = tanhf(i0 + m0);
      const float tb = tanhf(i1 + m1);
      const float sc = 1.f / (1.f + expf(-(i2 + m2)));
      const float sd = 1.f / (1.f + expf(-(i3 + m3)));
      const float se = 1.f / (1.f + expf(-(i4 + m4)));
      const float a = 1.f + ta;
      const float b = 1.5f * (1.f + tb);
      const float c = 0.3f + 0.7f * sc;
      const float d = 0.03f * sd;
      const float e = 1.f + se;
      const float hfn_v = (1.f - c) * hf + c * tanhf(i5 + (a + b * hf * hf - hs) * hf);
      const float eh  = e * hf;
      const float eh2 = eh * eh;
      const float hsn_v = hs * (1.f - d) + d * eh2 * eh2;
      hf_own[tid] = hfn_v;
      hs_own[tid] = hsn_v;
      hfw[(j0 + jj) * 64 + r] = hfn_v;
      out[(size_t)r * 524288 + (size_t)st * 512 + j0 + jj] = hfn_v;
      if (st == LSTEP - 1) {
        out[(size_t)33554432 + (size_t)r * 512 + j0 + jj] = hfn_v;
      }
    }
    gbar(cnt, st + 1);
  }
}

extern "C" void kernel_launch(void* const* d_in, const int* in_sizes, int n_in,
                              void* d_out, int out_size, void* d_ws, size_t ws_size,
                              hipStream_t stream) {
  (void)in_sizes; (void)n_in; (void)out_size; (void)ws_size;
  const float* u  = (const float*)d_in[0];
  const float* h0 = (const float*)d_in[1];
  const float* Wi = (const float*)d_in[2];
  const float* bi = (const float*)d_in[3];
  const float* Wm = (const float*)d_in[4];
  const float* bm = (const float*)d_in[5];
  float* out = (float*)d_out;
  unsigned* cnt = (unsigned*)d_ws;
  float* hfA = (float*)((char*)d_ws + 8192);
  float* hfB = hfA + 512 * 64;
  hipMemsetAsync(d_ws, 0, 8192, stream);
  hipLaunchKernelGGL(fused_scan, dim3(NWG), dim3(NTH), 0, stream,
                     u, h0, Wi, bi, Wm, bm, out, hfA, hfB, cnt);
}

// Round 2
// 9331.055 us; speedup vs baseline: 3.7695x; 3.7695x over previous
//
#include <hip/hip_runtime.h>
#include <cstdint>
#include <cstddef>

#define NWG   256
#define NTH   512
#define LSTEP 1024

// ws layout:
// [0, 8192)              barrier counters (1025 used)
// [8192, 8192+131072)    hfA  (transposed [512][64] fp32)
// [8192+131072, +131072) hfB

__global__ void __launch_bounds__(NTH)
fused_scan(const float* __restrict__ u, const float* __restrict__ h0,
           const float* __restrict__ Wi, const float* __restrict__ bi,
           const float* __restrict__ Wm, const float* __restrict__ bm,
           float* __restrict__ out, float* __restrict__ hfA,
           float* __restrict__ hfB, unsigned* __restrict__ cnt)
{
  // LDS: 32768 + 8192 + 20480 + 12288 + 2560 + 512 + 512 + 64 + 64 = 77440 B
  __shared__ __align__(16) float wm_s[512 * 16]; // me-cols c=0..9 at slot (c/5)*8 + c%5
  __shared__ __align__(16) float wi_s[128 * 16]; // ie-cols c=0..11 at slot (c/3)*4 + c%3
  __shared__ float part[5120];     // me partials [kc8][r64][c10]
  __shared__ float ie_part[3072];  // ie partials [kc4][r64][c12] (dense c)
  __shared__ float me_s[640];      // reduced me [r64][c10]
  __shared__ float hf_own[128];    // [r64][jj2]
  __shared__ float hs_own[128];
  __shared__ float bm_s[16];
  __shared__ float bi_s[16];

  const int wg   = blockIdx.x;   // 0..255
  const int j0   = wg * 2;       // this WG owns hf columns j0, j0+1
  const int tid  = threadIdx.x;
  const int w    = tid >> 6;     // wave 0..7
  const int lane = tid & 63;

  // ---- one-time: Wm slice (512 k-rows x 10 cols), float2 loads, pitch-16 slots
  {
    const int k = tid;
    const float* wrow = Wm + (size_t)k * 2560 + j0;
    const float2 v0 = *(const float2*)(wrow + 0);
    const float2 v1 = *(const float2*)(wrow + 512);
    const float2 v2 = *(const float2*)(wrow + 1024);
    const float2 v3 = *(const float2*)(wrow + 1536);
    const float2 v4 = *(const float2*)(wrow + 2048);
    float* b = &wm_s[k * 16];
    b[0] = v0.x; b[1] = v0.y; b[2]  = v1.x; b[3]  = v1.y; b[4]  = v2.x;
    b[8] = v2.y; b[9] = v3.x; b[10] = v3.y; b[11] = v4.x; b[12] = v4.y;
  }
  // ---- one-time: Wi slice (128 k-rows x 12 cols)
  if (tid < 128) {
    const int k = tid;
    const float* wrow = Wi + (size_t)k * 3072 + j0;
    const float2 v0 = *(const float2*)(wrow + 0);
    const float2 v1 = *(const float2*)(wrow + 512);
    const float2 v2 = *(const float2*)(wrow + 1024);
    const float2 v3 = *(const float2*)(wrow + 1536);
    const float2 v4 = *(const float2*)(wrow + 2048);
    const float2 v5 = *(const float2*)(wrow + 2560);
    float* b = &wi_s[k * 16];
    b[0]  = v0.x; b[1]  = v0.y; b[2]  = v1.x; b[4]  = v1.y;
    b[5]  = v2.x; b[6]  = v2.y; b[8]  = v3.x; b[9]  = v3.y;
    b[10] = v4.x; b[12] = v4.y; b[13] = v5.x; b[14] = v5.y;
  }
  if (tid < 10) bm_s[tid] = bm[(tid >> 1) * 512 + j0 + (tid & 1)];
  if (tid >= 32 && tid < 44) {
    const int c = tid - 32;
    bi_s[c] = bi[(c >> 1) * 512 + j0 + (c & 1)];
  }
  // ---- init own hf/hs from h0, publish hf slice (agent-scope, through to MALL)
  if (tid < 128) {
    const int r = tid >> 1, jj = tid & 1;
    const float f = h0[(size_t)r * 512 + j0 + jj];
    const float s = h0[(size_t)32768 + r * 512 + j0 + jj];
    hf_own[tid] = f;
    hs_own[tid] = s;
    __hip_atomic_store(&hfA[(j0 + jj) * 64 + r], f, __ATOMIC_RELAXED,
                       __HIP_MEMORY_SCOPE_AGENT);
  }

  // ---- ie partial compute for step stp (reads u + wi_s, writes ie_part) ----
  auto ie_compute = [&](int stp) {
    const int kc   = w >> 1;                 // 0..3, k in [kc*32, kc*32+32)
    const int tile = ((w & 1) << 6) + lane;  // 0..127
    const int rg   = tile >> 2;              // 0..31
    const int cg   = tile & 3;               // ie-cols cg*3..cg*3+2
    const int rr   = rg * 2;
    const int cb   = cg * 4;                 // wi_s slot base
    const int kb2  = kc * 32;
    const float* up0 = u + (size_t)rr * 131072 + (size_t)stp * 128 + kb2;
    const float* up1 = up0 + 131072;
    float a00 = 0, a01 = 0, a02 = 0, a10 = 0, a11 = 0, a12 = 0;
#define IE_K(KQ, X0, X1)                                                   \
    {                                                                      \
      const int k_ = kb2 + kk * 4 + (KQ);                                  \
      const float2 wab = *(const float2*)&wi_s[k_ * 16 + cb];              \
      const float  wc  = wi_s[k_ * 16 + cb + 2];                           \
      a00 += (X0) * wab.x; a01 += (X0) * wab.y; a02 += (X0) * wc;          \
      a10 += (X1) * wab.x; a11 += (X1) * wab.y; a12 += (X1) * wc;          \
    }
    #pragma unroll
    for (int kk = 0; kk < 8; ++kk) {
      const float4 x0 = *(const float4*)(up0 + kk * 4);
      const float4 x1 = *(const float4*)(up1 + kk * 4);
      IE_K(0, x0.x, x1.x)
      IE_K(1, x0.y, x1.y)
      IE_K(2, x0.z, x1.z)
      IE_K(3, x0.w, x1.w)
    }
#undef IE_K
    float* pp = &ie_part[kc * 768 + rr * 12 + cg * 3];
    pp[0]  = a00; pp[1]  = a01; pp[2]  = a02;
    pp[12] = a10; pp[13] = a11; pp[14] = a12;
  };

  // ---- prologue barrier 0 (overlapped with ie(0)) ----
  asm volatile("s_waitcnt vmcnt(0)" ::: "memory");
  __syncthreads();
  if (tid == 0)
    __hip_atomic_fetch_add(&cnt[0], 1u, __ATOMIC_RELAXED, __HIP_MEMORY_SCOPE_AGENT);
  ie_compute(0);
  if (tid == 0) {
    while (__hip_atomic_load(&cnt[0], __ATOMIC_RELAXED, __HIP_MEMORY_SCOPE_AGENT)
           < (unsigned)NWG) {}
  }
  __syncthreads();

  for (int st = 0; st < LSTEP; ++st) {
    const float* __restrict__ hfc = (st & 1) ? hfB : hfA;
    float* __restrict__ hfw       = (st & 1) ? hfA : hfB;

    // ======== phase 1: me partials. wave w handles k in [w*64, w*64+64) ====
    {
      const int rg    = lane >> 1;   // 0..31 -> batch rows 2rg, 2rg+1
      const int cg    = lane & 1;    // 0..1  -> me-cols cg*5 .. cg*5+4
      const int cslot = cg * 8;
      const int kb    = w * 64;
      const unsigned long long* hq = (const unsigned long long*)hfc; // [k][32] f2
      float acc00 = 0, acc01 = 0, acc02 = 0, acc03 = 0, acc04 = 0;
      float acc10 = 0, acc11 = 0, acc12 = 0, acc13 = 0, acc14 = 0;

#define LOADHF(K)                                                           \
      ({ union { unsigned long long uu; float2 ff; } t_;                   \
         t_.uu = __hip_atomic_load(&hq[(K) * 32 + rg], __ATOMIC_RELAXED,   \
                                   __HIP_MEMORY_SCOPE_AGENT);              \
         t_.ff; })

      float2 pf0 = LOADHF(kb + 0);
      float2 pf1 = LOADHF(kb + 1);
      float2 pf2 = LOADHF(kb + 2);
      float2 pf3 = LOADHF(kb + 3);
      float2 pf4 = LOADHF(kb + 4);
      float2 pf5 = LOADHF(kb + 5);
      float2 pf6 = LOADHF(kb + 6);
      float2 pf7 = LOADHF(kb + 7);

#define ME_ITER(K_, PFV, PF_STMT)                                          \
      {                                                                    \
        const float2 cur = PFV;                                            \
        PF_STMT;                                                           \
        const float4 w4 = *(const float4*)&wm_s[(K_) * 16 + cslot];        \
        const float  we = wm_s[(K_) * 16 + cslot + 4];                     \
        acc00 += cur.x * w4.x; acc01 += cur.x * w4.y;                      \
        acc02 += cur.x * w4.z; acc03 += cur.x * w4.w;                      \
        acc04 += cur.x * we;                                               \
        acc10 += cur.y * w4.x; acc11 += cur.y * w4.y;                      \
        acc12 += cur.y * w4.z; acc13 += cur.y * w4.w;                      \
        acc14 += cur.y * we;                                               \
      }

      for (int ki8 = 0; ki8 < 56; ki8 += 8) {
        const int kk = kb + ki8;
        ME_ITER(kk + 0, pf0, pf0 = LOADHF(kk + 8))
        ME_ITER(kk + 1, pf1, pf1 = LOADHF(kk + 9))
        ME_ITER(kk + 2, pf2, pf2 = LOADHF(kk + 10))
        ME_ITER(kk + 3, pf3, pf3 = LOADHF(kk + 11))
        ME_ITER(kk + 4, pf4, pf4 = LOADHF(kk + 12))
        ME_ITER(kk + 5, pf5, pf5 = LOADHF(kk + 13))
        ME_ITER(kk + 6, pf6, pf6 = LOADHF(kk + 14))
        ME_ITER(kk + 7, pf7, pf7 = LOADHF(kk + 15))
      }
      ME_ITER(kb + 56, pf0, )
      ME_ITER(kb + 57, pf1, )
      ME_ITER(kb + 58, pf2, )
      ME_ITER(kb + 59, pf3, )
      ME_ITER(kb + 60, pf4, )
      ME_ITER(kb + 61, pf5, )
      ME_ITER(kb + 62, pf6, )
      ME_ITER(kb + 63, pf7, )
#undef ME_ITER
#undef LOADHF

      const int rr = rg * 2;
      float* pp = &part[w * 640 + rr * 10 + cg * 5];
      pp[0]  = acc00; pp[1]  = acc01; pp[2]  = acc02; pp[3]  = acc03; pp[4]  = acc04;
      pp[10] = acc10; pp[11] = acc11; pp[12] = acc12; pp[13] = acc13; pp[14] = acc14;
    }
    __syncthreads();

    // ======== phase 2: reduce me partials (+bm) into me_s ========
    {
      float v = bm_s[tid % 10];
      #pragma unroll
      for (int kc = 0; kc < 8; ++kc) v += part[kc * 640 + tid];
      me_s[tid] = v;
      if (tid < 128) {
        const int o = tid + 512;
        float v2 = bm_s[o % 10];
        #pragma unroll
        for (int kc = 0; kc < 8; ++kc) v2 += part[kc * 640 + o];
        me_s[o] = v2;
      }
    }
    __syncthreads();

    // ======== phase 3: elementwise gate update for own (r, jj) ========
    if (tid < 128) {
      const int r = tid >> 1, jj = tid & 1;
      const float m0 = me_s[r * 10 + 0 + jj];
      const float m1 = me_s[r * 10 + 2 + jj];
      const float m2 = me_s[r * 10 + 4 + jj];
      const float m3 = me_s[r * 10 + 6 + jj];
      const float m4 = me_s[r * 10 + 8 + jj];
      float i0 = bi_s[0 + jj], i1 = bi_s[2 + jj], i2 = bi_s[4 + jj];
      float i3 = bi_s[6 + jj], i4 = bi_s[8 + jj], i5 = bi_s[10 + jj];
      #pragma unroll
      for (int kc = 0; kc < 4; ++kc) {
        const float* pp = &ie_part[kc * 768 + r * 12];
        i0 += pp[0 + jj]; i1 += pp[2 + jj]; i2 += pp[4 + jj];
        i3 += pp[6 + jj]; i4 += pp[8 + jj]; i5 += pp[10 + jj];
      }
      const float hf = hf_own[tid];
      const float hs = hs_own[tid];
      const float ta = tanhf(i0 + m0);
      const float tb = tanhf(i1 + m1);
      const float sc = 1.f / (1.f + expf(-(i2 + m2)));
      const float sd = 1.f / (1.f + expf(-(i3 + m3)));
      const float se = 1.f / (1.f + expf(-(i4 + m4)));
      const float a = 1.f + ta;
      const float b = 1.5f * (1.f + tb);
      const float c = 0.3f + 0.7f * sc;
      const float d = 0.03f * sd;
      const float e = 1.f + se;
      const float hfn_v = (1.f - c) * hf + c * tanhf(i5 + (a + b * hf * hf - hs) * hf);
      const float eh  = e * hf;
      const float eh2 = eh * eh;
      const float hsn_v = hs * (1.f - d) + d * eh2 * eh2;
      hf_own[tid] = hfn_v;
      hs_own[tid] = hsn_v;
      __hip_atomic_store(&hfw[(j0 + jj) * 64 + r], hfn_v, __ATOMIC_RELAXED,
                         __HIP_MEMORY_SCOPE_AGENT);
      out[(size_t)r * 524288 + (size_t)st * 512 + j0 + jj] = hfn_v;
      if (st == LSTEP - 1) {
        out[(size_t)33554432 + (size_t)r * 512 + j0 + jj] = hfn_v;
      }
    }

    // ======== barrier arrive; overlap ie(st+1); then wait ========
    asm volatile("s_waitcnt vmcnt(0)" ::: "memory"); // hf(st+1) stores at MALL
    __syncthreads();
    if (tid == 0)
      __hip_atomic_fetch_add(&cnt[st + 1], 1u, __ATOMIC_RELAXED,
                             __HIP_MEMORY_SCOPE_AGENT);
    if (st + 1 < LSTEP) ie_compute(st + 1);
    if (tid == 0) {
      while (__hip_atomic_load(&cnt[st + 1], __ATOMIC_RELAXED,
                               __HIP_MEMORY_SCOPE_AGENT) < (unsigned)NWG) {}
    }
    __syncthreads();
  }
}

extern "C" void kernel_launch(void* const* d_in, const int* in_sizes, int n_in,
                              void* d_out, int out_size, void* d_ws, size_t ws_size,
                              hipStream_t stream) {
  (void)in_sizes; (void)n_in; (void)out_size; (void)ws_size;
  const float* u  = (const float*)d_in[0];
  const float* h0 = (const float*)d_in[1];
  const float* Wi = (const float*)d_in[2];
  const float* bi = (const float*)d_in[3];
  const float* Wm = (const float*)d_in[4];
  const float* bm = (const float*)d_in[5];
  float* out = (float*)d_out;
  unsigned* cnt = (unsigned*)d_ws;
  float* hfA = (float*)((char*)d_ws + 8192);
  float* hfB = hfA + 512 * 64;
  hipMemsetAsync(d_ws, 0, 8192, stream);
  hipLaunchKernelGGL(fused_scan, dim3(NWG), dim3(NTH), 0, stream,
                     u, h0, Wi, bi, Wm, bm, out, hfA, hfB, cnt);
}

// Round 3
// 7313.335 us; speedup vs baseline: 4.8095x; 1.2759x over previous
//
#include <hip/hip_runtime.h>
#include <hip/hip_bf16.h>
#include <cstdint>
#include <cstddef>

#define NWG   256
#define NTH   512
#define LSTEP 1024

typedef __attribute__((ext_vector_type(8))) short short8;
typedef __attribute__((ext_vector_type(4))) float f32x4;

__device__ __forceinline__ unsigned f2bf_bits(float x) {
  __hip_bfloat16 h = __float2bfloat16(x);
  return (unsigned)__builtin_bit_cast(unsigned short, h);
}
__device__ __forceinline__ float bfbits2f(unsigned b) {
  return __bfloat162float(__builtin_bit_cast(__hip_bfloat16, (unsigned short)b));
}

// ws layout:
// [0, 8192)        barrier counters (1025 used)
// [8192, +65536)   hihA  bf16 plane [16 kt][64 row][32 kin]
// then hloA, hihB, hloB (65536 B each)

__global__ void __launch_bounds__(NTH)
fused_scan(const float* __restrict__ u, const float* __restrict__ h0,
           const float* __restrict__ Wi, const float* __restrict__ bi,
           const float* __restrict__ Wm, const float* __restrict__ bm,
           float* __restrict__ out,
           unsigned short* __restrict__ hihA, unsigned short* __restrict__ hloA,
           unsigned short* __restrict__ hihB, unsigned short* __restrict__ hloB,
           unsigned* __restrict__ cnt)
{
  __shared__ __align__(16) float wi_s[128 * 16]; // ie cols c=0..11 at (c/3)*4+c%3
  __shared__ float part_s[2 * 64 * 17];          // MFMA partials [kh][row][col] p17
  __shared__ float me_s[64 * 17];                // reduced me [row][col] pitch 17
  __shared__ float ie_part[3072];                // ie partials [kc4][r64][c12]
  __shared__ float hf_own[128];                  // [r64][jj2]
  __shared__ float hs_own[128];
  __shared__ float bm_s[16];
  __shared__ float bi_s[16];

  const int wg   = blockIdx.x;
  const int j0   = wg * 2;       // owns hf columns j0, j0+1
  const int tid  = threadIdx.x;
  const int w    = tid >> 6;     // wave 0..7
  const int lane = tid & 63;

  const int mt   = w & 3;        // M-tile (rows mt*16..mt*16+15)
  const int kh   = w >> 2;       // k-half (k in [kh*256, kh*256+256))
  const int colf = lane & 15;    // fragment col / row-in-tile
  const int ksub = lane >> 4;    // 0..3

  // ---- one-time: Wm slice as bf16 hi/lo B-fragments (register-resident) ----
  short8 bh[8], bl[8];
  {
    const bool valid = colf < 10;
    const int  gcol  = valid ? ((colf >> 1) * 512 + j0 + (colf & 1)) : 0;
    #pragma unroll
    for (int kt = 0; kt < 8; ++kt) {
      const int k8 = (kh * 8 + kt) * 32 + ksub * 8;
      #pragma unroll
      for (int j = 0; j < 8; ++j) {
        const float wv = valid ? Wm[(size_t)(k8 + j) * 2560 + gcol] : 0.f;
        const unsigned hb = f2bf_bits(wv);
        const unsigned lb = f2bf_bits(wv - bfbits2f(hb));
        bh[kt][j] = (short)hb;
        bl[kt][j] = (short)lb;
      }
    }
  }
  // ---- one-time: Wi slice (128 k-rows x 12 cols) into LDS ----
  if (tid < 128) {
    const int k = tid;
    const float* wrow = Wi + (size_t)k * 3072 + j0;
    const float2 v0 = *(const float2*)(wrow + 0);
    const float2 v1 = *(const float2*)(wrow + 512);
    const float2 v2 = *(const float2*)(wrow + 1024);
    const float2 v3 = *(const float2*)(wrow + 1536);
    const float2 v4 = *(const float2*)(wrow + 2048);
    const float2 v5 = *(const float2*)(wrow + 2560);
    float* b = &wi_s[k * 16];
    b[0]  = v0.x; b[1]  = v0.y; b[2]  = v1.x; b[4]  = v1.y;
    b[5]  = v2.x; b[6]  = v2.y; b[8]  = v3.x; b[9]  = v3.y;
    b[10] = v4.x; b[12] = v4.y; b[13] = v5.x; b[14] = v5.y;
  }
  if (tid < 16) bm_s[tid] = (tid < 10) ? bm[(tid >> 1) * 512 + j0 + (tid & 1)] : 0.f;
  if (tid >= 32 && tid < 44) {
    const int c = tid - 32;
    bi_s[c] = bi[(c >> 1) * 512 + j0 + (c & 1)];
  }
  // ---- init own hf/hs from h0, publish bf16 hi/lo planes (sc1) ----
  if (tid < 128) {
    const int r = tid >> 1, jj = tid & 1;
    const int j = j0 + jj;
    const float f = h0[(size_t)r * 512 + j];
    const float s = h0[(size_t)32768 + r * 512 + j];
    hf_own[tid] = f;
    hs_own[tid] = s;
    const size_t eidx = ((size_t)((j >> 5) * 64 + r)) * 32 + (j & 31);
    const unsigned hb = f2bf_bits(f);
    const unsigned lb = f2bf_bits(f - bfbits2f(hb));
    asm volatile("global_store_short %0, %1, off sc1" :: "v"(hihA + eidx), "v"(hb) : "memory");
    asm volatile("global_store_short %0, %1, off sc1" :: "v"(hloA + eidx), "v"(lb) : "memory");
  }

  // ---- ie partial compute for step stp ----
  auto ie_compute = [&](int stp) {
    const int kc   = w >> 1;
    const int tile = ((w & 1) << 6) + lane;
    const int rg   = tile >> 2;
    const int cg   = tile & 3;
    const int rr   = rg * 2;
    const int cb   = cg * 4;
    const int kb2  = kc * 32;
    const float* up0 = u + (size_t)rr * 131072 + (size_t)stp * 128 + kb2;
    const float* up1 = up0 + 131072;
    float a00 = 0, a01 = 0, a02 = 0, a10 = 0, a11 = 0, a12 = 0;
#define IE_K(KQ, X0, X1)                                                   \
    {                                                                      \
      const int k_ = kb2 + kk * 4 + (KQ);                                  \
      const float2 wab = *(const float2*)&wi_s[k_ * 16 + cb];              \
      const float  wc  = wi_s[k_ * 16 + cb + 2];                           \
      a00 += (X0) * wab.x; a01 += (X0) * wab.y; a02 += (X0) * wc;          \
      a10 += (X1) * wab.x; a11 += (X1) * wab.y; a12 += (X1) * wc;          \
    }
    #pragma unroll
    for (int kk = 0; kk < 8; ++kk) {
      const float4 x0 = *(const float4*)(up0 + kk * 4);
      const float4 x1 = *(const float4*)(up1 + kk * 4);
      IE_K(0, x0.x, x1.x)
      IE_K(1, x0.y, x1.y)
      IE_K(2, x0.z, x1.z)
      IE_K(3, x0.w, x1.w)
    }
#undef IE_K
    float* pp = &ie_part[kc * 768 + rr * 12 + cg * 3];
    pp[0]  = a00; pp[1]  = a01; pp[2]  = a02;
    pp[12] = a10; pp[13] = a11; pp[14] = a12;
  };

  // ---- prologue barrier 0 (overlapped with ie(0)) ----
  asm volatile("s_waitcnt vmcnt(0)" ::: "memory");
  __syncthreads();
  if (tid == 0)
    __hip_atomic_fetch_add(&cnt[0], 1u, __ATOMIC_RELAXED, __HIP_MEMORY_SCOPE_AGENT);
  ie_compute(0);
  if (tid == 0) {
    while (__hip_atomic_load(&cnt[0], __ATOMIC_RELAXED, __HIP_MEMORY_SCOPE_AGENT)
           < (unsigned)NWG) {}
  }
  __syncthreads();

  for (int st = 0; st < LSTEP; ++st) {
    const unsigned short* __restrict__ rh = (st & 1) ? hihB : hihA;
    const unsigned short* __restrict__ rl = (st & 1) ? hloB : hloA;
    unsigned short* __restrict__ wh       = (st & 1) ? hihA : hihB;
    unsigned short* __restrict__ wl       = (st & 1) ? hloA : hloB;

    // ======== phase 1: me via split-bf16 MFMA ========
    {
      const int b = mt * 16 + colf;  // batch row of A fragment
      short8 ah[8], al[8];
      #pragma unroll
      for (int kt = 0; kt < 8; ++kt) {
        const size_t eoff = ((size_t)((kh * 8 + kt) * 64 + b)) * 32 + ksub * 8;
        asm volatile("global_load_dwordx4 %0, %1, off sc1"
                     : "=v"(ah[kt]) : "v"(rh + eoff) : "memory");
        asm volatile("global_load_dwordx4 %0, %1, off sc1"
                     : "=v"(al[kt]) : "v"(rl + eoff) : "memory");
      }
      asm volatile("s_waitcnt vmcnt(0)" ::: "memory");
      __builtin_amdgcn_sched_barrier(0);
      f32x4 acc = {0.f, 0.f, 0.f, 0.f};
      #pragma unroll
      for (int kt = 0; kt < 8; ++kt) {
        acc = __builtin_amdgcn_mfma_f32_16x16x32_bf16(ah[kt], bh[kt], acc, 0, 0, 0);
        acc = __builtin_amdgcn_mfma_f32_16x16x32_bf16(ah[kt], bl[kt], acc, 0, 0, 0);
        acc = __builtin_amdgcn_mfma_f32_16x16x32_bf16(al[kt], bh[kt], acc, 0, 0, 0);
      }
      #pragma unroll
      for (int i = 0; i < 4; ++i)
        part_s[(kh * 64 + mt * 16 + ksub * 4 + i) * 17 + colf] = acc[i];
    }
    __syncthreads();

    // ======== phase 2: reduce k-halves (+bm) into me_s ========
    {
      int e = tid;
      #pragma unroll
      for (int rep = 0; rep < 2; ++rep, e += 512) {
        const int row = e >> 4, c = e & 15;
        me_s[row * 17 + c] =
            part_s[row * 17 + c] + part_s[(64 + row) * 17 + c] + bm_s[c];
      }
    }
    __syncthreads();

    // ======== phase 3: elementwise gate update for own (r, jj) ========
    if (tid < 128) {
      const int r = tid >> 1, jj = tid & 1;
      const float m0 = me_s[r * 17 + 0 + jj];
      const float m1 = me_s[r * 17 + 2 + jj];
      const float m2 = me_s[r * 17 + 4 + jj];
      const float m3 = me_s[r * 17 + 6 + jj];
      const float m4 = me_s[r * 17 + 8 + jj];
      float i0 = bi_s[0 + jj], i1 = bi_s[2 + jj], i2 = bi_s[4 + jj];
      float i3 = bi_s[6 + jj], i4 = bi_s[8 + jj], i5 = bi_s[10 + jj];
      #pragma unroll
      for (int kc = 0; kc < 4; ++kc) {
        const float* pp = &ie_part[kc * 768 + r * 12];
        i0 += pp[0 + jj]; i1 += pp[2 + jj]; i2 += pp[4 + jj];
        i3 += pp[6 + jj]; i4 += pp[8 + jj]; i5 += pp[10 + jj];
      }
      const float hf = hf_own[tid];
      const float hs = hs_own[tid];
      const float ta = tanhf(i0 + m0);
      const float tb = tanhf(i1 + m1);
      const float sc = 1.f / (1.f + expf(-(i2 + m2)));
      const float sd = 1.f / (1.f + expf(-(i3 + m3)));
      const float se = 1.f / (1.f + expf(-(i4 + m4)));
      const float a = 1.f + ta;
      const float b = 1.5f * (1.f + tb);
      const float c = 0.3f + 0.7f * sc;
      const float d = 0.03f * sd;
      const float e = 1.f + se;
      const float hfn_v = (1.f - c) * hf + c * tanhf(i5 + (a + b * hf * hf - hs) * hf);
      const float eh  = e * hf;
      const float eh2 = eh * eh;
      const float hsn_v = hs * (1.f - d) + d * eh2 * eh2;
      hf_own[tid] = hfn_v;
      hs_own[tid] = hsn_v;
      const int j = j0 + jj;
      const size_t eidx = ((size_t)((j >> 5) * 64 + r)) * 32 + (j & 31);
      const unsigned hb = f2bf_bits(hfn_v);
      const unsigned lb = f2bf_bits(hfn_v - bfbits2f(hb));
      asm volatile("global_store_short %0, %1, off sc1" :: "v"(wh + eidx), "v"(hb) : "memory");
      asm volatile("global_store_short %0, %1, off sc1" :: "v"(wl + eidx), "v"(lb) : "memory");
      out[(size_t)r * 524288 + (size_t)st * 512 + j] = hfn_v;
      if (st == LSTEP - 1) {
        out[(size_t)33554432 + (size_t)r * 512 + j] = hfn_v;
      }
    }

    // ======== barrier arrive; overlap ie(st+1); then wait ========
    asm volatile("s_waitcnt vmcnt(0)" ::: "memory");
    __syncthreads();
    if (tid == 0)
      __hip_atomic_fetch_add(&cnt[st + 1], 1u, __ATOMIC_RELAXED,
                             __HIP_MEMORY_SCOPE_AGENT);
    if (st + 1 < LSTEP) ie_compute(st + 1);
    if (tid == 0) {
      while (__hip_atomic_load(&cnt[st + 1], __ATOMIC_RELAXED,
                               __HIP_MEMORY_SCOPE_AGENT) < (unsigned)NWG) {}
    }
    __syncthreads();
  }
}

extern "C" void kernel_launch(void* const* d_in, const int* in_sizes, int n_in,
                              void* d_out, int out_size, void* d_ws, size_t ws_size,
                              hipStream_t stream) {
  (void)in_sizes; (void)n_in; (void)out_size; (void)ws_size;
  const float* u  = (const float*)d_in[0];
  const float* h0 = (const float*)d_in[1];
  const float* Wi = (const float*)d_in[2];
  const float* bi = (const float*)d_in[3];
  const float* Wm = (const float*)d_in[4];
  const float* bm = (const float*)d_in[5];
  float* out = (float*)d_out;
  unsigned* cnt = (unsigned*)d_ws;
  unsigned short* hihA = (unsigned short*)((char*)d_ws + 8192);
  unsigned short* hloA = hihA + 32768;
  unsigned short* hihB = hloA + 32768;
  unsigned short* hloB = hihB + 32768;
  hipMemsetAsync(d_ws, 0, 8192, stream);
  hipLaunchKernelGGL(fused_scan, dim3(NWG), dim3(NTH), 0, stream,
                     u, h0, Wi, bi, Wm, bm, out, hihA, hloA, hihB, hloB, cnt);
}

// Round 4
// 6705.109 us; speedup vs baseline: 5.2458x; 1.0907x over previous
//
#include <hip/hip_runtime.h>
#include <hip/hip_bf16.h>
#include <cstdint>
#include <cstddef>

#define NWG   256
#define NTH   512
#define LSTEP 1024

typedef __attribute__((ext_vector_type(8))) short short8;
typedef __attribute__((ext_vector_type(4))) float f32x4;
typedef __attribute__((ext_vector_type(4))) unsigned int u32x4;

__device__ __forceinline__ unsigned f2bf_bits(float x) {
  __hip_bfloat16 h = __float2bfloat16(x);
  return (unsigned)__builtin_bit_cast(unsigned short, h);
}
__device__ __forceinline__ float bfbits2f(unsigned b) {
  return __bfloat162float(__builtin_bit_cast(__hip_bfloat16, (unsigned short)b));
}

// ws: [0,8192) counters | stateA 131072 B (uint hi|lo [64 rows][512 cols]) | stateB

__global__ void __launch_bounds__(NTH, 2)
fused_scan(const float* __restrict__ u, const float* __restrict__ h0,
           const float* __restrict__ Wi, const float* __restrict__ bi,
           const float* __restrict__ Wm, const float* __restrict__ bm,
           float* __restrict__ out, unsigned* __restrict__ stateA,
           unsigned* __restrict__ stateB, unsigned* __restrict__ cnt)
{
  __shared__ float part_s[5120];   // [kh8][r8][c80]
  __shared__ float me_s[640];      // [r8][c80]
  __shared__ float ie_part[3072];  // [kc4][r8][c96]
  __shared__ float hf_own[128];    // [r8][j16]
  __shared__ float hs_own[128];
  __shared__ float bm_s[80];
  __shared__ float bi_s[96];

  const int wg   = blockIdx.x;
  const int jc   = wg & 31;        // 32 col-groups
  const int bc   = wg >> 5;        // 8 batch-groups
  const int j0   = jc * 16;        // owns hf cols j0..j0+15
  const int r0   = bc * 8;         // owns batch rows r0..r0+7
  const int tid  = threadIdx.x;
  const int w    = tid >> 6;       // wave 0..7 = K-slice (me) / (kc,nh) (ie)
  const int lane = tid & 63;
  const int colf = lane & 15;
  const int ksub = lane >> 4;

  // ---- one-time small LDS ----
  if (tid < 80) bm_s[tid] = bm[(tid % 5) * 512 + j0 + tid / 5];
  if (tid >= 128 && tid < 224) {
    const int c = tid - 128;
    bi_s[c] = bi[(c % 6) * 512 + j0 + c / 6];
  }
  // ---- init own hf/hs, publish packed state (sc1, coalesced 64B/row) ----
  if (tid < 128) {
    const int r = tid >> 4, j16 = tid & 15;
    const float f = h0[(size_t)(r0 + r) * 512 + j0 + j16];
    const float s = h0[(size_t)32768 + (size_t)(r0 + r) * 512 + j0 + j16];
    hf_own[tid] = f;
    hs_own[tid] = s;
    const unsigned hb = f2bf_bits(f);
    const unsigned lb = f2bf_bits(f - bfbits2f(hb));
    const unsigned pk = hb | (lb << 16);
    unsigned* dst = stateA + (size_t)(r0 + r) * 512 + j0 + j16;
    asm volatile("global_store_dword %0, %1, off sc1" :: "v"(dst), "v"(pk) : "memory");
  }
  asm volatile("s_waitcnt vmcnt(0)" ::: "memory");
  __syncthreads();
  if (tid == 0)
    __hip_atomic_fetch_add(&cnt[0], 1u, __ATOMIC_RELAXED, __HIP_MEMORY_SCOPE_AGENT);

  // ---- B-fragment gathers (overlap barrier 0) ----
  short8 bh[5][2], bl[5][2];                 // Wm slice, hi/lo
  #pragma unroll
  for (int nt = 0; nt < 5; ++nt) {
    const int c = nt * 16 + colf;            // 0..79
    const int gcol = (c % 5) * 512 + j0 + c / 5;
    #pragma unroll
    for (int kt = 0; kt < 2; ++kt) {
      #pragma unroll
      for (int j = 0; j < 8; ++j) {
        const int kg = w * 64 + kt * 32 + ksub * 8 + j;
        const float wv = Wm[(size_t)kg * 2560 + gcol];
        const unsigned hb = f2bf_bits(wv);
        bh[nt][kt][j] = (short)hb;
        bl[nt][kt][j] = (short)f2bf_bits(wv - bfbits2f(hb));
      }
    }
  }
  const int iekc = w & 3;                    // ie k-chunk (32 k)
  const int ienh = w >> 2;                   // ie n-half (3 ntiles)
  short8 bih[3], bil[3];                     // Wi slice, hi/lo
  #pragma unroll
  for (int nt = 0; nt < 3; ++nt) {
    const int c = (ienh * 3 + nt) * 16 + colf;   // 0..95
    const int gcol = (c % 6) * 512 + j0 + c / 6;
    #pragma unroll
    for (int j = 0; j < 8; ++j) {
      const int kg = iekc * 32 + ksub * 8 + j;
      const float wv = Wi[(size_t)kg * 3072 + gcol];
      const unsigned hb = f2bf_bits(wv);
      bih[nt][j] = (short)hb;
      bil[nt][j] = (short)f2bf_bits(wv - bfbits2f(hb));
    }
  }

  // ---- ie via MFMA for step stp (writes ie_part) ----
  auto ie_compute = [&](int stp) {
    const int rloc = lane & 7;               // rows dup for lane&15>=8 (unused D rows)
    const float* up = u + (size_t)(r0 + rloc) * 131072 + (size_t)stp * 128
                        + iekc * 32 + ksub * 8;
    const float4 x0 = *(const float4*)up;
    const float4 x1 = *(const float4*)(up + 4);
    const float xv[8] = {x0.x, x0.y, x0.z, x0.w, x1.x, x1.y, x1.z, x1.w};
    short8 ah, al;
    #pragma unroll
    for (int j = 0; j < 8; ++j) {
      const unsigned hb = f2bf_bits(xv[j]);
      ah[j] = (short)hb;
      al[j] = (short)f2bf_bits(xv[j] - bfbits2f(hb));
    }
    f32x4 acc[3];
    #pragma unroll
    for (int nt = 0; nt < 3; ++nt) { acc[nt][0]=0.f; acc[nt][1]=0.f; acc[nt][2]=0.f; acc[nt][3]=0.f; }
    #pragma unroll
    for (int nt = 0; nt < 3; ++nt) {
      acc[nt] = __builtin_amdgcn_mfma_f32_16x16x32_bf16(ah, bih[nt], acc[nt], 0, 0, 0);
      acc[nt] = __builtin_amdgcn_mfma_f32_16x16x32_bf16(ah, bil[nt], acc[nt], 0, 0, 0);
      acc[nt] = __builtin_amdgcn_mfma_f32_16x16x32_bf16(al, bih[nt], acc[nt], 0, 0, 0);
    }
    if (lane < 32) {
      const int rb = (lane >> 4) * 4;
      #pragma unroll
      for (int nt = 0; nt < 3; ++nt)
        #pragma unroll
        for (int i = 0; i < 4; ++i)
          ie_part[iekc * 768 + (rb + i) * 96 + (ienh * 3 + nt) * 16 + colf] = acc[nt][i];
    }
  };

  ie_compute(0);
  if (tid == 0) {
    while (__hip_atomic_load(&cnt[0], __ATOMIC_RELAXED, __HIP_MEMORY_SCOPE_AGENT)
           < (unsigned)NWG) {}
  }
  __syncthreads();

  for (int st = 0; st < LSTEP; ++st) {
    const unsigned* __restrict__ scur = (st & 1) ? stateB : stateA;
    unsigned* __restrict__ snxt       = (st & 1) ? stateA : stateB;

    // ======== phase 1: me = hf @ Wm via split-bf16 MFMA ========
    {
      const int rloc = lane & 7;
      const unsigned* base = scur + (size_t)(r0 + rloc) * 512 + w * 64 + ksub * 8;
      u32x4 q0, q1, q2, q3;
      asm volatile("global_load_dwordx4 %0, %1, off sc1" : "=v"(q0) : "v"(base)      : "memory");
      asm volatile("global_load_dwordx4 %0, %1, off sc1" : "=v"(q1) : "v"(base + 4)  : "memory");
      asm volatile("global_load_dwordx4 %0, %1, off sc1" : "=v"(q2) : "v"(base + 32) : "memory");
      asm volatile("global_load_dwordx4 %0, %1, off sc1" : "=v"(q3) : "v"(base + 36) : "memory");
      asm volatile("s_waitcnt vmcnt(0)" ::: "memory");
      __builtin_amdgcn_sched_barrier(0);
      short8 ah[2], al[2];
      #pragma unroll
      for (int j = 0; j < 4; ++j) {
        ah[0][j]     = (short)(q0[j] & 0xffffu);  al[0][j]     = (short)(q0[j] >> 16);
        ah[0][j + 4] = (short)(q1[j] & 0xffffu);  al[0][j + 4] = (short)(q1[j] >> 16);
        ah[1][j]     = (short)(q2[j] & 0xffffu);  al[1][j]     = (short)(q2[j] >> 16);
        ah[1][j + 4] = (short)(q3[j] & 0xffffu);  al[1][j + 4] = (short)(q3[j] >> 16);
      }
      f32x4 acc[5];
      #pragma unroll
      for (int nt = 0; nt < 5; ++nt) { acc[nt][0]=0.f; acc[nt][1]=0.f; acc[nt][2]=0.f; acc[nt][3]=0.f; }
      #pragma unroll
      for (int nt = 0; nt < 5; ++nt)
        #pragma unroll
        for (int kt = 0; kt < 2; ++kt) {
          acc[nt] = __builtin_amdgcn_mfma_f32_16x16x32_bf16(ah[kt], bh[nt][kt], acc[nt], 0, 0, 0);
          acc[nt] = __builtin_amdgcn_mfma_f32_16x16x32_bf16(ah[kt], bl[nt][kt], acc[nt], 0, 0, 0);
          acc[nt] = __builtin_amdgcn_mfma_f32_16x16x32_bf16(al[kt], bh[nt][kt], acc[nt], 0, 0, 0);
        }
      if (lane < 32) {
        const int rb = (lane >> 4) * 4;
        #pragma unroll
        for (int nt = 0; nt < 5; ++nt)
          #pragma unroll
          for (int i = 0; i < 4; ++i)
            part_s[(w * 8 + rb + i) * 80 + nt * 16 + colf] = acc[nt][i];
      }
    }
    __syncthreads();

    // ======== phase 2: reduce K-slices (+bm) ========
    for (int e = tid; e < 640; e += NTH) {
      float v = bm_s[e % 80];
      #pragma unroll
      for (int kh = 0; kh < 8; ++kh) v += part_s[kh * 640 + e];
      me_s[e] = v;
    }
    __syncthreads();

    // ======== phase 3: gates + state update + publish ========
    if (tid < 128) {
      const int r = tid >> 4, j16 = tid & 15;
      const float* mrow = &me_s[r * 80 + j16 * 5];
      const float m0 = mrow[0], m1 = mrow[1], m2 = mrow[2], m3 = mrow[3], m4 = mrow[4];
      const float* brow = &bi_s[j16 * 6];
      float i0 = brow[0], i1 = brow[1], i2 = brow[2];
      float i3 = brow[3], i4 = brow[4], i5 = brow[5];
      #pragma unroll
      for (int kc = 0; kc < 4; ++kc) {
        const float* pp = &ie_part[kc * 768 + r * 96 + j16 * 6];
        i0 += pp[0]; i1 += pp[1]; i2 += pp[2]; i3 += pp[3]; i4 += pp[4]; i5 += pp[5];
      }
      const float hf = hf_own[tid];
      const float hs = hs_own[tid];
      const float ta = tanhf(i0 + m0);
      const float tb = tanhf(i1 + m1);
      const float sc = 1.f / (1.f + expf(-(i2 + m2)));
      const float sd = 1.f / (1.f + expf(-(i3 + m3)));
      const float se = 1.f / (1.f + expf(-(i4 + m4)));
      const float a = 1.f + ta;
      const float b = 1.5f * (1.f + tb);
      const float c = 0.3f + 0.7f * sc;
      const float d = 0.03f * sd;
      const float e = 1.f + se;
      const float hfn_v = (1.f - c) * hf + c * tanhf(i5 + (a + b * hf * hf - hs) * hf);
      const float eh  = e * hf;
      const float eh2 = eh * eh;
      const float hsn_v = hs * (1.f - d) + d * eh2 * eh2;
      hf_own[tid] = hfn_v;
      hs_own[tid] = hsn_v;
      const unsigned hb = f2bf_bits(hfn_v);
      const unsigned lb = f2bf_bits(hfn_v - bfbits2f(hb));
      const unsigned pk = hb | (lb << 16);
      unsigned* dst = snxt + (size_t)(r0 + r) * 512 + j0 + j16;
      asm volatile("global_store_dword %0, %1, off sc1" :: "v"(dst), "v"(pk) : "memory");
      out[(size_t)(r0 + r) * 524288 + (size_t)st * 512 + j0 + j16] = hfn_v;
      if (st == LSTEP - 1)
        out[(size_t)33554432 + (size_t)(r0 + r) * 512 + j0 + j16] = hfn_v;
    }

    // ======== barrier arrive; overlap ie(st+1); wait ========
    asm volatile("s_waitcnt vmcnt(0)" ::: "memory");
    __syncthreads();
    if (tid == 0)
      __hip_atomic_fetch_add(&cnt[st + 1], 1u, __ATOMIC_RELAXED,
                             __HIP_MEMORY_SCOPE_AGENT);
    if (st + 1 < LSTEP) ie_compute(st + 1);
    if (tid == 0) {
      while (__hip_atomic_load(&cnt[st + 1], __ATOMIC_RELAXED,
                               __HIP_MEMORY_SCOPE_AGENT) < (unsigned)NWG) {}
    }
    __syncthreads();
  }
}

extern "C" void kernel_launch(void* const* d_in, const int* in_sizes, int n_in,
                              void* d_out, int out_size, void* d_ws, size_t ws_size,
                              hipStream_t stream) {
  (void)in_sizes; (void)n_in; (void)out_size; (void)ws_size;
  const float* u  = (const float*)d_in[0];
  const float* h0 = (const float*)d_in[1];
  const float* Wi = (const float*)d_in[2];
  const float* bi = (const float*)d_in[3];
  const float* Wm = (const float*)d_in[4];
  const float* bm = (const float*)d_in[5];
  float* out = (float*)d_out;
  unsigned* cnt = (unsigned*)d_ws;
  unsigned* stateA = (unsigned*)((char*)d_ws + 8192);
  unsigned* stateB = stateA + 32768;
  hipMemsetAsync(d_ws, 0, 8192, stream);
  hipLaunchKernelGGL(fused_scan, dim3(NWG), dim3(NTH), 0, stream,
                     u, h0, Wi, bi, Wm, bm, out, stateA, stateB, cnt);
}

// Round 5
// 3997.953 us; speedup vs baseline: 8.7979x; 1.6771x over previous
//
#include <hip/hip_runtime.h>
#include <hip/hip_bf16.h>
#include <cstdint>
#include <cstddef>

#define NWG   256
#define NTH   512
#define LSTEP 1024

typedef __attribute__((ext_vector_type(8))) short short8;
typedef __attribute__((ext_vector_type(4))) float f32x4;
typedef __attribute__((ext_vector_type(4))) unsigned int u32x4;

__device__ __forceinline__ unsigned f2bf_bits(float x) {
  __hip_bfloat16 h = __float2bfloat16(x);
  return (unsigned)__builtin_bit_cast(unsigned short, h);
}
__device__ __forceinline__ float bfbits2f(unsigned b) {
  return __bfloat162float(__builtin_bit_cast(__hip_bfloat16, (unsigned short)b));
}
__device__ __forceinline__ float ftanh(float x) {
  const float ax = fminf(fabsf(x), 15.f);
  const float e  = __expf(-2.f * ax);
  const float t  = (1.f - e) / (1.f + e);
  return copysignf(t, x);
}
__device__ __forceinline__ float fsig(float x) {
  const float xx = fmaxf(fminf(x, 30.f), -30.f);
  return 1.f / (1.f + __expf(-xx));
}

// ws: [0,2048) rel[bc]@256B | [2048,35840) cnt[bc*1056+b] | [36864,+128K) stateA | stateB

__global__ void __launch_bounds__(NTH, 2)
fused_scan(const float* __restrict__ u, const float* __restrict__ h0,
           const float* __restrict__ Wi, const float* __restrict__ bi,
           const float* __restrict__ Wm, const float* __restrict__ bm,
           float* __restrict__ out, unsigned* __restrict__ stateA,
           unsigned* __restrict__ stateB, unsigned* __restrict__ rel,
           unsigned* __restrict__ cnt)
{
  __shared__ float part_s[5120];   // [kh8][r8][c80]
  __shared__ float ie_part[3072];  // [kc4][r8][c96]
  __shared__ float hf_own[128];    // [r8][j16]
  __shared__ float hs_own[128];
  __shared__ float bm_s[80];
  __shared__ float bi_s[96];

  const int wg   = blockIdx.x;
  const int jc   = wg & 31;        // 32 col-groups
  const int bc   = wg >> 5;        // 8 batch-groups (sync domain!)
  const int j0   = jc * 16;
  const int r0   = bc * 8;
  const int tid  = threadIdx.x;
  const int w    = tid >> 6;
  const int lane = tid & 63;
  const int colf = lane & 15;
  const int ksub = lane >> 4;

  unsigned* mycnt = cnt + bc * 1056;
  unsigned* myrel = rel + bc * 64;

  // ---- one-time small LDS ----
  if (tid < 80) bm_s[tid] = bm[(tid % 5) * 512 + j0 + tid / 5];
  if (tid >= 128 && tid < 224) {
    const int c = tid - 128;
    bi_s[c] = bi[(c % 6) * 512 + j0 + c / 6];
  }
  // ---- init own hf/hs, publish packed state ----
  if (tid < 128) {
    const int r = tid >> 4, j16 = tid & 15;
    const float f = h0[(size_t)(r0 + r) * 512 + j0 + j16];
    const float s = h0[(size_t)32768 + (size_t)(r0 + r) * 512 + j0 + j16];
    hf_own[tid] = f;
    hs_own[tid] = s;
    const unsigned hb = f2bf_bits(f);
    const unsigned lb = f2bf_bits(f - bfbits2f(hb));
    const unsigned pk = hb | (lb << 16);
    unsigned* dst = stateA + (size_t)(r0 + r) * 512 + j0 + j16;
    asm volatile("global_store_dword %0, %1, off sc1" :: "v"(dst), "v"(pk) : "memory");
  }
  asm volatile("s_waitcnt vmcnt(0)" ::: "memory");
  __syncthreads();
  if (tid == 0) {
    const unsigned old = __hip_atomic_fetch_add(&mycnt[0], 1u, __ATOMIC_RELAXED,
                                                __HIP_MEMORY_SCOPE_AGENT);
    if (old == 31u)
      __hip_atomic_store(myrel, 1u, __ATOMIC_RELAXED, __HIP_MEMORY_SCOPE_AGENT);
  }

  // ---- B-fragment gathers (overlap prologue barrier) ----
  short8 bh[5][2], bl[5][2];
  #pragma unroll
  for (int nt = 0; nt < 5; ++nt) {
    const int c = nt * 16 + colf;
    const int gcol = (c % 5) * 512 + j0 + c / 5;
    #pragma unroll
    for (int kt = 0; kt < 2; ++kt) {
      #pragma unroll
      for (int j = 0; j < 8; ++j) {
        const int kg = w * 64 + kt * 32 + ksub * 8 + j;
        const float wv = Wm[(size_t)kg * 2560 + gcol];
        const unsigned hb = f2bf_bits(wv);
        bh[nt][kt][j] = (short)hb;
        bl[nt][kt][j] = (short)f2bf_bits(wv - bfbits2f(hb));
      }
    }
  }
  const int iekc = w & 3;
  const int ienh = w >> 2;
  short8 bih[3], bil[3];
  #pragma unroll
  for (int nt = 0; nt < 3; ++nt) {
    const int c = (ienh * 3 + nt) * 16 + colf;
    const int gcol = (c % 6) * 512 + j0 + c / 6;
    #pragma unroll
    for (int j = 0; j < 8; ++j) {
      const int kg = iekc * 32 + ksub * 8 + j;
      const float wv = Wi[(size_t)kg * 3072 + gcol];
      const unsigned hb = f2bf_bits(wv);
      bih[nt][j] = (short)hb;
      bil[nt][j] = (short)f2bf_bits(wv - bfbits2f(hb));
    }
  }

  // ---- ie via MFMA for step stp ----
  auto ie_compute = [&](int stp) {
    const int rloc = lane & 7;
    const float* up = u + (size_t)(r0 + rloc) * 131072 + (size_t)stp * 128
                        + iekc * 32 + ksub * 8;
    const float4 x0 = *(const float4*)up;
    const float4 x1 = *(const float4*)(up + 4);
    const float xv[8] = {x0.x, x0.y, x0.z, x0.w, x1.x, x1.y, x1.z, x1.w};
    short8 ah, al;
    #pragma unroll
    for (int j = 0; j < 8; ++j) {
      const unsigned hb = f2bf_bits(xv[j]);
      ah[j] = (short)hb;
      al[j] = (short)f2bf_bits(xv[j] - bfbits2f(hb));
    }
    f32x4 acc[3];
    #pragma unroll
    for (int nt = 0; nt < 3; ++nt) { acc[nt][0]=0.f; acc[nt][1]=0.f; acc[nt][2]=0.f; acc[nt][3]=0.f; }
    #pragma unroll
    for (int nt = 0; nt < 3; ++nt) {
      acc[nt] = __builtin_amdgcn_mfma_f32_16x16x32_bf16(ah, bih[nt], acc[nt], 0, 0, 0);
      acc[nt] = __builtin_amdgcn_mfma_f32_16x16x32_bf16(ah, bil[nt], acc[nt], 0, 0, 0);
      acc[nt] = __builtin_amdgcn_mfma_f32_16x16x32_bf16(al, bih[nt], acc[nt], 0, 0, 0);
    }
    if (lane < 32) {
      const int rb = (lane >> 4) * 4;
      #pragma unroll
      for (int nt = 0; nt < 3; ++nt)
        #pragma unroll
        for (int i = 0; i < 4; ++i)
          ie_part[iekc * 768 + (rb + i) * 96 + (ienh * 3 + nt) * 16 + colf] = acc[nt][i];
    }
  };

  ie_compute(0);
  if (tid == 0) {
    while (__hip_atomic_load(myrel, __ATOMIC_RELAXED, __HIP_MEMORY_SCOPE_AGENT) < 1u)
      __builtin_amdgcn_s_sleep(1);
  }
  __syncthreads();

  for (int st = 0; st < LSTEP; ++st) {
    const unsigned* __restrict__ scur = (st & 1) ? stateB : stateA;
    unsigned* __restrict__ snxt       = (st & 1) ? stateA : stateB;

    // ======== phase 1: me = hf @ Wm via split-bf16 MFMA ========
    {
      const int rloc = lane & 7;
      const unsigned* base = scur + (size_t)(r0 + rloc) * 512 + w * 64 + ksub * 8;
      u32x4 q0, q1, q2, q3;
      asm volatile("global_load_dwordx4 %0, %1, off sc1" : "=v"(q0) : "v"(base)      : "memory");
      asm volatile("global_load_dwordx4 %0, %1, off sc1" : "=v"(q1) : "v"(base + 4)  : "memory");
      asm volatile("global_load_dwordx4 %0, %1, off sc1" : "=v"(q2) : "v"(base + 32) : "memory");
      asm volatile("global_load_dwordx4 %0, %1, off sc1" : "=v"(q3) : "v"(base + 36) : "memory");
      asm volatile("s_waitcnt vmcnt(0)" ::: "memory");
      __builtin_amdgcn_sched_barrier(0);
      short8 ah[2], al[2];
      #pragma unroll
      for (int j = 0; j < 4; ++j) {
        ah[0][j]     = (short)(q0[j] & 0xffffu);  al[0][j]     = (short)(q0[j] >> 16);
        ah[0][j + 4] = (short)(q1[j] & 0xffffu);  al[0][j + 4] = (short)(q1[j] >> 16);
        ah[1][j]     = (short)(q2[j] & 0xffffu);  al[1][j]     = (short)(q2[j] >> 16);
        ah[1][j + 4] = (short)(q3[j] & 0xffffu);  al[1][j + 4] = (short)(q3[j] >> 16);
      }
      f32x4 acc[5];
      #pragma unroll
      for (int nt = 0; nt < 5; ++nt) { acc[nt][0]=0.f; acc[nt][1]=0.f; acc[nt][2]=0.f; acc[nt][3]=0.f; }
      #pragma unroll
      for (int nt = 0; nt < 5; ++nt)
        #pragma unroll
        for (int kt = 0; kt < 2; ++kt) {
          acc[nt] = __builtin_amdgcn_mfma_f32_16x16x32_bf16(ah[kt], bh[nt][kt], acc[nt], 0, 0, 0);
          acc[nt] = __builtin_amdgcn_mfma_f32_16x16x32_bf16(ah[kt], bl[nt][kt], acc[nt], 0, 0, 0);
          acc[nt] = __builtin_amdgcn_mfma_f32_16x16x32_bf16(al[kt], bh[nt][kt], acc[nt], 0, 0, 0);
        }
      if (lane < 32) {
        const int rb = (lane >> 4) * 4;
        #pragma unroll
        for (int nt = 0; nt < 5; ++nt)
          #pragma unroll
          for (int i = 0; i < 4; ++i)
            part_s[(w * 8 + rb + i) * 80 + nt * 16 + colf] = acc[nt][i];
      }
    }
    __syncthreads();

    // ======== phase 2: fused reduce + gates + publish (2 waves) ========
    if (tid < 128) {
      const int r = tid >> 4, j16 = tid & 15;
      float m[5];
      #pragma unroll
      for (int g = 0; g < 5; ++g) {
        float v = bm_s[j16 * 5 + g];
        #pragma unroll
        for (int kh = 0; kh < 8; ++kh) v += part_s[kh * 640 + r * 80 + j16 * 5 + g];
        m[g] = v;
      }
      float iacc[6];
      #pragma unroll
      for (int g = 0; g < 6; ++g) {
        float v = bi_s[j16 * 6 + g];
        #pragma unroll
        for (int kc = 0; kc < 4; ++kc) v += ie_part[kc * 768 + r * 96 + j16 * 6 + g];
        iacc[g] = v;
      }
      const float hf = hf_own[tid];
      const float hs = hs_own[tid];
      const float a = 1.f + ftanh(iacc[0] + m[0]);
      const float b = 1.5f * (1.f + ftanh(iacc[1] + m[1]));
      const float c = 0.3f + 0.7f * fsig(iacc[2] + m[2]);
      const float d = 0.03f * fsig(iacc[3] + m[3]);
      const float e = 1.f + fsig(iacc[4] + m[4]);
      const float hfn_v = (1.f - c) * hf + c * ftanh(iacc[5] + (a + b * hf * hf - hs) * hf);
      const float eh  = e * hf;
      const float eh2 = eh * eh;
      const float hsn_v = hs * (1.f - d) + d * eh2 * eh2;
      hf_own[tid] = hfn_v;
      hs_own[tid] = hsn_v;
      const unsigned hb = f2bf_bits(hfn_v);
      const unsigned lb = f2bf_bits(hfn_v - bfbits2f(hb));
      const unsigned pk = hb | (lb << 16);
      unsigned* dst = snxt + (size_t)(r0 + r) * 512 + j0 + j16;
      asm volatile("global_store_dword %0, %1, off sc1" :: "v"(dst), "v"(pk) : "memory");
      out[(size_t)(r0 + r) * 524288 + (size_t)st * 512 + j0 + j16] = hfn_v;
      if (st == LSTEP - 1)
        out[(size_t)33554432 + (size_t)(r0 + r) * 512 + j0 + j16] = hfn_v;
    }

    // ======== per-bc-group barrier: arrive; overlap ie(st+1); wait ========
    asm volatile("s_waitcnt vmcnt(0)" ::: "memory");
    __syncthreads();
    if (tid == 0) {
      const unsigned old = __hip_atomic_fetch_add(&mycnt[st + 1], 1u, __ATOMIC_RELAXED,
                                                  __HIP_MEMORY_SCOPE_AGENT);
      if (old == 31u)
        __hip_atomic_store(myrel, (unsigned)(st + 2), __ATOMIC_RELAXED,
                           __HIP_MEMORY_SCOPE_AGENT);
    }
    if (st + 1 < LSTEP) ie_compute(st + 1);
    if (tid == 0) {
      while (__hip_atomic_load(myrel, __ATOMIC_RELAXED, __HIP_MEMORY_SCOPE_AGENT)
             < (unsigned)(st + 2))
        __builtin_amdgcn_s_sleep(1);
    }
    __syncthreads();
  }
}

extern "C" void kernel_launch(void* const* d_in, const int* in_sizes, int n_in,
                              void* d_out, int out_size, void* d_ws, size_t ws_size,
                              hipStream_t stream) {
  (void)in_sizes; (void)n_in; (void)out_size; (void)ws_size;
  const float* u  = (const float*)d_in[0];
  const float* h0 = (const float*)d_in[1];
  const float* Wi = (const float*)d_in[2];
  const float* bi = (const float*)d_in[3];
  const float* Wm = (const float*)d_in[4];
  const float* bm = (const float*)d_in[5];
  float* out = (float*)d_out;
  unsigned* rel    = (unsigned*)d_ws;                       // [0, 2048)
  unsigned* cnt    = (unsigned*)((char*)d_ws + 2048);       // [2048, 35840)
  unsigned* stateA = (unsigned*)((char*)d_ws + 36864);
  unsigned* stateB = stateA + 32768;
  hipMemsetAsync(d_ws, 0, 36864, stream);
  hipLaunchKernelGGL(fused_scan, dim3(NWG), dim3(NTH), 0, stream,
                     u, h0, Wi, bi, Wm, bm, out, stateA, stateB, rel, cnt);
}